// Round 1
// 730.094 us; speedup vs baseline: 1.0277x; 1.0277x over previous
//
#include <hip/hip_runtime.h>

// Problem constants (from reference)
constexpr int B       = 64;
constexpr int F       = 4096;   // FOLD
constexpr int K       = 32;     // KERNEL
constexpr int O       = 512;    // OUT_CH
constexpr int STRIDE  = 16;
constexpr int PAD     = 8;
constexpr int IN_LEN  = 65536;

// Tiling: each block owns FT consecutive f's, full O, all 64 batches.
constexpr int FT      = 8;      // f per block -> grid = 512 blocks
constexpr int BLOCK   = 512;    // 8 waves
constexpr int XROW    = 68;     // padded x_s row stride (floats) to spread write banks

// out[b,f,o] = sum_k xp[b, f*16 + k] * w[f,k,o],  xp = x zero-padded by 8
__global__ __launch_bounds__(BLOCK, 2)
void Local_39152921870765_kernel(const float* __restrict__ x,
                                 const float* __restrict__ w,
                                 float* __restrict__ out)
{
    __shared__ float w_s[2][K][O];     // 128 KiB, double-buffered weight tile
    __shared__ float x_s[2][K][XROW];  // 17 KiB,  double-buffered x window [k][b]

    const int tid  = threadIdx.x;
    const int lane = tid & 63;
    const int wid  = tid >> 6;        // wave 0..7
    const int f0   = blockIdx.x * FT;

    // compute mapping: 8 batches x 8 o per thread.
    // wave-uniform batch group -> x_s reads are pure 64-lane broadcasts.
    const int og = lane;              // o = og*4..og*4+3  and  og*4+256..+259
    const int bb = wid * 8;           // 8 consecutive batches per wave

    // x staging mapping: one float4 of the 32-wide window per thread
    const int sb = tid >> 3;          // batch 0..63
    const int sq = tid & 7;           // float4 slot 0..7 (covers k = 4*sq..4*sq+3)

    // ---- async DMA of one f's weight tile (64 KB) into w_s[buf] ----
    // 64 chunks of 1 KB; wave-uniform LDS base + lane*16B (linear), per-lane global src.
    auto stage_w = [&](int f, int buf) {
        const float* gbase = w + (size_t)f * (K * O);
        #pragma unroll
        for (int i = 0; i < 8; ++i) {
            const int c    = wid * 8 + i;   // chunk id 0..63
            const int k    = c >> 1;
            const int half = c & 1;
            const float* g = gbase + k * O + half * 256 + lane * 4;
            __builtin_amdgcn_global_load_lds(
                (const __attribute__((address_space(1))) void*)g,
                (__attribute__((address_space(3))) void*)&w_s[buf][k][half * 256],
                16, 0, 0);
        }
    };

    // ---- x window load (to regs) and transposed LDS write ----
    auto load_x = [&](int f) -> float4 {
        const int p0 = f * STRIDE - PAD + sq * 4;   // float4 never straddles a boundary
        float4 v = make_float4(0.f, 0.f, 0.f, 0.f);
        if (p0 >= 0 && p0 <= IN_LEN - 4)
            v = *(const float4*)(x + (size_t)sb * IN_LEN + p0);
        return v;
    };
    auto put_x = [&](int buf, float4 v) {
        x_s[buf][sq * 4 + 0][sb] = v.x;
        x_s[buf][sq * 4 + 1][sb] = v.y;
        x_s[buf][sq * 4 + 2][sb] = v.z;
        x_s[buf][sq * 4 + 3][sb] = v.w;
    };

    // ---- prologue: stage f0 into buffer 0 ----
    stage_w(f0, 0);
    put_x(0, load_x(f0));
    __syncthreads();

    int cur = 0;
    for (int ft = 0; ft < FT; ++ft) {
        const int f   = f0 + ft;
        const int nxt = cur ^ 1;
        const bool more = (ft + 1 < FT);

        // issue next-f prefetch BEFORE compute: HBM latency hides under the k-loop
        float4 xpre;
        if (more) {
            stage_w(f + 1, nxt);
            xpre = load_x(f + 1);
        }

        float acc[8][8];
        #pragma unroll
        for (int i = 0; i < 8; ++i)
            #pragma unroll
            for (int j = 0; j < 8; ++j) acc[i][j] = 0.0f;

        #pragma unroll 4
        for (int k = 0; k < K; ++k) {
            const float4 wa  = *(const float4*)&w_s[cur][k][og * 4];        // contiguous 1KB/wave
            const float4 wb  = *(const float4*)&w_s[cur][k][og * 4 + 256];
            const float4 xa  = *(const float4*)&x_s[cur][k][bb];            // 64-lane broadcast
            const float4 xb4 = *(const float4*)&x_s[cur][k][bb + 4];
            const float xv[8] = {xa.x, xa.y, xa.z, xa.w, xb4.x, xb4.y, xb4.z, xb4.w};
            const float wv[8] = {wa.x, wa.y, wa.z, wa.w, wb.x, wb.y, wb.z, wb.w};
            #pragma unroll
            for (int i = 0; i < 8; ++i)
                #pragma unroll
                for (int j = 0; j < 8; ++j)
                    acc[i][j] = fmaf(xv[i], wv[j], acc[i][j]);
        }

        // ---- store f: per wave-instr 1 KB contiguous ----
        #pragma unroll
        for (int i = 0; i < 8; ++i) {
            const size_t base = ((size_t)(bb + i) * F + f) * O + og * 4;
            *(float4*)(out + base)       = make_float4(acc[i][0], acc[i][1], acc[i][2], acc[i][3]);
            *(float4*)(out + base + 256) = make_float4(acc[i][4], acc[i][5], acc[i][6], acc[i][7]);
        }

        // finish the x double-buffer (compiler inserts the exact vmcnt for xpre)
        if (more) put_x(nxt, xpre);
        __syncthreads();   // drains the w prefetch (had the whole k-loop to land)
        cur = nxt;
    }
}

extern "C" void kernel_launch(void* const* d_in, const int* in_sizes, int n_in,
                              void* d_out, int out_size, void* d_ws, size_t ws_size,
                              hipStream_t stream) {
    const float* x = (const float*)d_in[0];   // (64, 65536) fp32
    const float* w = (const float*)d_in[1];   // (4096, 32, 512) fp32
    float* out = (float*)d_out;               // (64, 4096, 512) fp32

    dim3 grid(F / FT);                        // 512 blocks, 2 per CU
    Local_39152921870765_kernel<<<grid, BLOCK, 0, stream>>>(x, w, out);
}